// Round 3
// baseline (1191.096 us; speedup 1.0000x reference)
//
#include <hip/hip_runtime.h>
#include <math.h>

// ---------------- problem constants ----------------
#define N_TOK  98304   // B*M
#define NE     6
#define NPAIR  36      // ordered (e1,e2) pairs, e1*6+e2
#define TCOL   120     // T*2
#define RMARGIN 0.06f  // gap(v2,v3) threshold for fp32 repair (bf16 router err ~5e-3 sigma)

// ---------------- workspace byte offsets ----------------
#define WS_SE    0         // float[8]  : per-expert prob sums (atomic)
#define WS_CNT   32        // int[36]   : pair counts (atomic)
#define WS_CUR   192       // int[36]   : placement cursors
#define WS_BAS   352       // int[37]   : pair bases (prefix), bas[36]=N
#define WS_RCNT  504       // int       : repair count (zeroed by memset 512)
#define WS_TB    512       // int[37]   : pair tile bases
#define WS_PAIR  1024      // uint[N]   : e1 | e2<<8
#define WS_W1A   394240    // float[N]  : top-1 weight
#define WS_W2A   787456    // float[N]  : top-2 weight
#define WS_LIST  1180672   // int[N]    : repair list, then pair-bucketed tokens
#define WS_RW1T  1573888   // float[256*128] : router W1 transposed [c][k] (repair)
#define WS_RW3T  1704960   // float[6*128]   : router W3 transposed [e][j] (repair)
#define WS_FRAG  1708032   // bf16 expert weights, MFMA-B-fragment layout
#define WS_RFRAG 3575808   // bf16 router weight frags (hi only, 67584 el)

// expert fragment offsets (bf16 elements)
#define EOFF      155648
#define FOFF_TW1  0
#define FOFF_TW2  32768
#define FOFF_TW3  98304
#define FOFF_SW1  131072
#define FOFF_SW2  147456

// router fragment offsets (bf16 elements within WS_RFRAG)
#define RF_W1 0        // 128x256 -> 32768
#define RF_W2 32768    // 256x128 -> 32768
#define RF_W3 65536    // 128x16(6 padded) -> 2048

// ---------------- K2 (expert) LDS layout: 45056 B -> 3 blocks/CU ----------
#define XS_OFF   0         // 64 x 136 bf16 = 17408 (X; later H2 cols 0..127)
#define BUF_OFF  17408     // 64 x 136 bf16 = 17408 (HS1 / H1a / H1b / H2 cols 128..255)
#define HS2_OFF  34816     // 64 x 72 bf16  = 9216
#define TOK_OFF  44032     // int[64]
#define WA_OFF   44288     // float[64]
#define WB_OFF   44544     // float[64]
#define SC_OFF   44800     // float[64]
#define SM_BYTES 45056

// ---------------- router2 LDS (32-token blocks): 26656 B -> 6 blocks/CU ----
#define RX_OFF   0         // 32 x 136 bf16 = 8704 (X; later H2)
#define RH1_OFF  8704      // 32 x 264 bf16 = 16896
#define RLG_OFF  25600     // 32 x 8 fp32 = 1024
#define RSRED    26624     // float[6]
#define RSM_BYTES 26656

typedef short short8 __attribute__((ext_vector_type(8)));
typedef float f32x4  __attribute__((ext_vector_type(4)));

__device__ __forceinline__ short f2bf(float f) {          // RNE fp32 -> bf16
  unsigned int u = __builtin_bit_cast(unsigned int, f);
  u = u + 0x7FFFu + ((u >> 16) & 1u);
  return (short)(u >> 16);
}
__device__ __forceinline__ float bf2f(short s) {
  unsigned int u = ((unsigned int)(unsigned short)s) << 16;
  return __builtin_bit_cast(float, u);
}
__device__ __forceinline__ float gelu_exact(float x) {
  return 0.5f * x * (1.0f + erff(x * 0.7071067811865476f));
}
// fast tanh-GELU (err ~3e-4): x * sigmoid(2*0.79788*(x+0.044715x^3)) in exp2 domain
__device__ __forceinline__ float gelu_fast(float x) {
  float x2 = x * x;
  float u  = x * fmaf(0.1029454f, x2, 2.3021188f);
  float d  = 1.0f + exp2f(-u);
  return x * __builtin_amdgcn_rcpf(d);
}

// =====================================================================
// K0: weight preprocessing.
//  [0,456): expert weights -> bf16 B-frag layout
//  [456,489): router weights -> bf16 B-frags (hi only)
//  [489,620): fp32 transposes of rW1 / rW3 (repair path)
// B-frag: tile(nt,kt): lane l holds B[k=kt*32+(l>>4)*8+j][n=nt*16+(l&15)]
// =====================================================================
__global__ __launch_bounds__(256) void k_prep(
    const float* __restrict__ rW1, const float* __restrict__ rW2,
    const float* __restrict__ rW3,
    const float* __restrict__ tW1, const float* __restrict__ tW2,
    const float* __restrict__ tW3, const float* __restrict__ sW1,
    const float* __restrict__ sW2, char* __restrict__ ws)
{
  const int tid = threadIdx.x, blk = blockIdx.x;
  const int lane = tid & 63, l15 = lane & 15, quad = lane >> 4;
  if (blk < 456) {                       // 1824 expert tiles, 1 wave each
    const int g = blk * 4 + (tid >> 6);
    const int e = g / 304, r = g - e * 304;
    const float* src; int KT, Nreal, dstoff, nt, kt;
    if (r < 64)       { KT=4; src=tW1+e*32768; Nreal=256; dstoff=FOFF_TW1; kt=r&3;        nt=r>>2; }
    else if (r < 192) { int r2=r-64;  KT=8; src=tW2+e*65536; Nreal=256; dstoff=FOFF_TW2; kt=r2&7; nt=r2>>3; }
    else if (r < 256) { int r2=r-192; KT=8; src=tW3+e*30720; Nreal=120; dstoff=FOFF_TW3; kt=r2&7; nt=r2>>3; }
    else if (r < 288) { int r2=r-256; KT=4; src=sW1+e*16384; Nreal=128; dstoff=FOFF_SW1; kt=r2&3; nt=r2>>2; }
    else              { int r2=r-288; KT=4; src=sW2+e*8192;  Nreal=64;  dstoff=FOFF_SW2; kt=r2&3; nt=r2>>2; }
    const int n = nt * 16 + l15;
    short8 v;
    #pragma unroll
    for (int j = 0; j < 8; ++j) {
      int k = kt * 32 + quad * 8 + j;
      float f = (n < Nreal) ? src[k * Nreal + n] : 0.f;
      v[j] = f2bf(f);
    }
    short* dst = (short*)(ws + WS_FRAG) + (size_t)e * EOFF + dstoff + (nt * KT + kt) * 512 + lane * 8;
    *(short8*)dst = v;
  } else if (blk < 489) {                // 132 router tiles, 1 wave each
    const int g = (blk - 456) * 4 + (tid >> 6);   // 0..131
    const float* src; int KT, Nreal, kt, nt, doff;
    if (g < 64)       { KT=4; src=rW1; Nreal=256; kt=g&3; nt=g>>2; doff=RF_W1; }
    else if (g < 128) { int g2=g-64;  KT=8; src=rW2; Nreal=128; kt=g2&7; nt=g2>>3; doff=RF_W2; }
    else              { int g2=g-128; KT=4; src=rW3; Nreal=6;   kt=g2;   nt=0;     doff=RF_W3; }
    const int n = nt * 16 + l15;
    short8 v;
    #pragma unroll
    for (int j = 0; j < 8; ++j) {
      int k = kt * 32 + quad * 8 + j;
      float f = (n < Nreal) ? src[k * Nreal + n] : 0.f;
      v[j] = f2bf(f);
    }
    *(short8*)((short*)(ws + WS_RFRAG) + doff + (nt * KT + kt) * 512 + lane * 8) = v;
  } else {                               // router transposes (fp32, repair path)
    const int t = (blk - 489) * 256 + tid;
    if (t < 32768) {
      int c = t >> 7, k = t & 127;
      ((float*)(ws + WS_RW1T))[t] = rW1[k * 256 + c];
    } else if (t < 33536) {
      int t2 = t - 32768, e = t2 >> 7, j = t2 & 127;
      ((float*)(ws + WS_RW3T))[t2] = rW3[j * 6 + e];
    }
  }
}

// =====================================================================
// Generic MFMA tile GEMM: MT m-tiles, KT k-tiles, NTW n-tiles per wave.
// A from LDS (bf16 row-major, stride aStride shorts), B frags from global.
// B index: (( (ntBase+ntl)*BST + kt )*512 + lane*8). Accumulates into acc.
// =====================================================================
template<int MT, int KT, int NTW, int BST>
__device__ __forceinline__ void gemm_g(
    const char* sm, int aOff, int aStride,
    const short* __restrict__ bfrag, int ntBase,
    f32x4 (&acc)[MT][NTW], int lane)
{
  const int l15 = lane & 15, quad = lane >> 4;
  #pragma unroll
  for (int kt = 0; kt < KT; ++kt) {
    short8 a[MT];
    #pragma unroll
    for (int mt = 0; mt < MT; ++mt) {
      const short* ap = (const short*)(sm + aOff) + (mt * 16 + l15) * aStride + kt * 32 + quad * 8;
      a[mt] = *(const short8*)ap;
    }
    #pragma unroll
    for (int ntl = 0; ntl < NTW; ++ntl) {
      short8 b = *(const short8*)(bfrag + (size_t)((ntBase + ntl) * BST + kt) * 512 + lane * 8);
      #pragma unroll
      for (int mt = 0; mt < MT; ++mt)
        acc[mt][ntl] = __builtin_amdgcn_mfma_f32_16x16x32_bf16(a[mt], b, acc[mt][ntl], 0, 0, 0);
    }
  }
}

template<int MT, int NTW>
__device__ __forceinline__ void epi_gelu(
    char* sm, int outOff, int outStride, const float* __restrict__ bias,
    f32x4 (&acc)[MT][NTW], int ntBase, int lane)
{
  const int l15 = lane & 15, quad = lane >> 4;
  #pragma unroll
  for (int ntl = 0; ntl < NTW; ++ntl) {
    const int n = (ntBase + ntl) * 16 + l15;
    float bv = bias[n];
    #pragma unroll
    for (int mt = 0; mt < MT; ++mt) {
      #pragma unroll
      for (int i = 0; i < 4; ++i) {
        const int r = mt * 16 + quad * 4 + i;   // C/D: row = quad*4+reg, col = l15
        ((short*)(sm + outOff))[r * outStride + n] = f2bf(gelu_fast(acc[mt][ntl][i] + bv));
      }
    }
  }
}

// =====================================================================
// K1: pure-bf16 MFMA router, 32 tokens/block, 4 waves, 6 blocks/CU.
// Flags gap(v2,v3) < RMARGIN tokens for fp32 repair.
// =====================================================================
__global__ __launch_bounds__(256) void k_router2(
    const float* __restrict__ xg,
    const float* __restrict__ b1, const float* __restrict__ b2,
    const float* __restrict__ b3,
    float* __restrict__ probs_out, char* __restrict__ ws)
{
  __shared__ __attribute__((aligned(16))) char sm[RSM_BYTES];
  const int tid = threadIdx.x;
  const int lane = tid & 63, w = tid >> 6;
  const int l15 = lane & 15, quad = lane >> 4;
  const int tok0 = blockIdx.x * 32;
  const short* rf = (const short*)(ws + WS_RFRAG);
  const f32x4 z = {0.f, 0.f, 0.f, 0.f};

  if (tid < NE) ((float*)(sm + RSRED))[tid] = 0.f;

  { // stage X -> bf16
    const int t = tid >> 3, seg = tid & 7;
    const float4* src = (const float4*)(xg + (size_t)(tok0 + t) * 128 + seg * 16);
    unsigned int* dst = (unsigned int*)((short*)(sm + RX_OFF) + t * 136 + seg * 16);
    #pragma unroll
    for (int i = 0; i < 4; ++i) {
      float4 v = src[i];
      dst[i*2+0] = (unsigned int)(unsigned short)f2bf(v.x) | ((unsigned int)(unsigned short)f2bf(v.y) << 16);
      dst[i*2+1] = (unsigned int)(unsigned short)f2bf(v.z) | ((unsigned int)(unsigned short)f2bf(v.w) << 16);
    }
  }
  __syncthreads();

  { // L1: X[32x128] * W1 -> H1[32x256]
    f32x4 acc[2][4];
    #pragma unroll
    for (int mt = 0; mt < 2; ++mt)
      #pragma unroll
      for (int ntl = 0; ntl < 4; ++ntl) acc[mt][ntl] = z;
    gemm_g<2, 4, 4, 4>(sm, RX_OFF, 136, rf + RF_W1, w * 4, acc, lane);
    epi_gelu<2, 4>(sm, RH1_OFF, 264, b1, acc, w * 4, lane);
  }
  __syncthreads();

  { // L2: H1[32x256] * W2 -> H2[32x128] (overlays X)
    f32x4 acc[2][2];
    #pragma unroll
    for (int mt = 0; mt < 2; ++mt) { acc[mt][0] = z; acc[mt][1] = z; }
    gemm_g<2, 8, 2, 8>(sm, RH1_OFF, 264, rf + RF_W2, w * 2, acc, lane);
    epi_gelu<2, 2>(sm, RX_OFF, 136, b2, acc, w * 2, lane);
  }
  __syncthreads();

  // L3: H2[32x128] * W3 -> logits (waves 0,1)
  if (w < 2) {
    f32x4 acc[1][1]; acc[0][0] = z;
    gemm_g<1, 4, 1, 4>(sm, RX_OFF + w * 16 * 136 * 2, 136, rf + RF_W3, 0, acc, lane);
    if (l15 < NE) {
      const float bv = b3[l15];
      #pragma unroll
      for (int i = 0; i < 4; ++i) {
        const int r = w * 16 + quad * 4 + i;
        ((float*)(sm + RLG_OFF))[r * 8 + l15] = acc[0][0][i] + bv;
      }
    }
  }
  __syncthreads();

  // per-token: top-2, probs, repair flag
  if (tid < 32) {
    const int n = tok0 + tid;
    float l[NE];
    #pragma unroll
    for (int e = 0; e < NE; ++e) l[e] = ((float*)(sm + RLG_OFF))[tid * 8 + e];
    int e1 = 0; float v1 = l[0];
    #pragma unroll
    for (int e = 1; e < NE; ++e) if (l[e] > v1) { v1 = l[e]; e1 = e; }
    int e2 = -1; float v2 = -3.4e38f;
    #pragma unroll
    for (int e = 0; e < NE; ++e) if (e != e1 && l[e] > v2) { v2 = l[e]; e2 = e; }
    float v3 = -3.4e38f;
    #pragma unroll
    for (int e = 0; e < NE; ++e) if (e != e1 && e != e2 && l[e] > v3) v3 = l[e];

    float ew = expf(v2 - v1);
    float winv = 1.f / (1.f + ew);
    ((unsigned int*)(ws + WS_PAIR))[n] = (unsigned int)e1 | ((unsigned int)e2 << 8);
    ((float*)(ws + WS_W1A))[n] = winv;
    ((float*)(ws + WS_W2A))[n] = ew * winv;

    float s = 0.f;
    #pragma unroll
    for (int e = 0; e < NE; ++e) { l[e] = expf(l[e] - v1); s += l[e]; }
    float inv = 1.f / s;
    float* po = probs_out + (size_t)n * NE;
    #pragma unroll
    for (int e = 0; e < NE; ++e) {
      l[e] *= inv; po[e] = l[e];
      atomicAdd((float*)(sm + RSRED) + e, l[e]);
    }
    if (v2 - v3 < RMARGIN) {
      int idx = atomicAdd((int*)(ws + WS_RCNT), 1);
      ((int*)(ws + WS_LIST))[idx] = n;
    }
  }
  __syncthreads();
  if (tid < NE) atomicAdd((float*)(ws + WS_SE) + tid, ((float*)(sm + RSRED))[tid]);
}

// =====================================================================
// K1r: fp32 repair for gap-ambiguous tokens (one wave per token).
// =====================================================================
__global__ __launch_bounds__(256) void k_repair(
    const float* __restrict__ xg,
    const float* __restrict__ b1, const float* __restrict__ rW2,
    const float* __restrict__ b2, const float* __restrict__ b3,
    float* __restrict__ probs_out, char* __restrict__ ws)
{
  __shared__ float xs[4][128], h1b[4][256], h2b[4][128], lgb[4][8];
  const int tid = threadIdx.x, lane = tid & 63, w = tid >> 6;
  const int gw = blockIdx.x * 4 + w, NW = gridDim.x * 4;
  const int rc = *(const int*)(ws + WS_RCNT);
  const float* w1t = (const float*)(ws + WS_RW1T);
  const float* w3t = (const float*)(ws + WS_RW3T);

  for (int i = gw; i < rc; i += NW) {
    const int n = ((const int*)(ws + WS_LIST))[i];
    xs[w][lane]      = xg[(size_t)n * 128 + lane];
    xs[w][64 + lane] = xg[(size_t)n * 128 + 64 + lane];
    __builtin_amdgcn_s_waitcnt(0);
    #pragma unroll
    for (int c4 = 0; c4 < 4; ++c4) {
      const int c = c4 * 64 + lane;
      float acc = b1[c];
      const float* wr = w1t + c * 128;
      #pragma unroll 8
      for (int k = 0; k < 128; ++k) acc = fmaf(xs[w][k], wr[k], acc);
      h1b[w][c] = gelu_exact(acc);
    }
    __builtin_amdgcn_s_waitcnt(0);
    #pragma unroll
    for (int c2 = 0; c2 < 2; ++c2) {
      const int c = c2 * 64 + lane;
      float acc = b2[c];
      #pragma unroll 8
      for (int k = 0; k < 256; ++k) acc = fmaf(h1b[w][k], rW2[k * 128 + c], acc);
      h2b[w][c] = gelu_exact(acc);
    }
    __builtin_amdgcn_s_waitcnt(0);
    if (lane < NE) {
      float acc = b3[lane];
      const float* wr = w3t + lane * 128;
      #pragma unroll 8
      for (int k = 0; k < 128; ++k) acc = fmaf(h2b[w][k], wr[k], acc);
      lgb[w][lane] = acc;
    }
    __builtin_amdgcn_s_waitcnt(0);
    if (lane == 0) {
      float l[NE];
      #pragma unroll
      for (int e = 0; e < NE; ++e) l[e] = lgb[w][e];
      int e1 = 0; float v1 = l[0];
      #pragma unroll
      for (int e = 1; e < NE; ++e) if (l[e] > v1) { v1 = l[e]; e1 = e; }
      int e2 = -1; float v2 = -3.4e38f;
      #pragma unroll
      for (int e = 0; e < NE; ++e) if (e != e1 && l[e] > v2) { v2 = l[e]; e2 = e; }
      float ew = expf(v2 - v1);
      float winv = 1.f / (1.f + ew);
      ((unsigned int*)(ws + WS_PAIR))[n] = (unsigned int)e1 | ((unsigned int)e2 << 8);
      ((float*)(ws + WS_W1A))[n] = winv;
      ((float*)(ws + WS_W2A))[n] = ew * winv;
      float s = 0.f;
      #pragma unroll
      for (int e = 0; e < NE; ++e) { l[e] = expf(l[e] - v1); s += l[e]; }
      float inv = 1.f / s;
      float* po = probs_out + (size_t)n * NE;
      #pragma unroll
      for (int e = 0; e < NE; ++e) po[e] = l[e] * inv;
    }
  }
}

// =====================================================================
// K1c0: pair counts (after repair)
// =====================================================================
__global__ __launch_bounds__(256) void k_count(char* __restrict__ ws)
{
  __shared__ int lcnt[NPAIR];
  const int tid = threadIdx.x;
  if (tid < NPAIR) lcnt[tid] = 0;
  __syncthreads();
  const int n = blockIdx.x * 256 + tid;
  unsigned int pr = ((const unsigned int*)(ws + WS_PAIR))[n];
  atomicAdd(&lcnt[(int)(pr & 255u) * NE + (int)((pr >> 8) & 255u)], 1);
  __syncthreads();
  if (tid < NPAIR && lcnt[tid]) atomicAdd((int*)(ws + WS_CNT) + tid, lcnt[tid]);
}

// =====================================================================
// K1b: serial 36-bucket prefix scan + aux_loss (tiny)
// =====================================================================
__global__ void k_scan(char* __restrict__ ws, float* __restrict__ aux_out)
{
  if (threadIdx.x == 0 && blockIdx.x == 0) {
    int* cnt = (int*)(ws + WS_CNT);
    int* cur = (int*)(ws + WS_CUR);
    int* bas = (int*)(ws + WS_BAS);
    int* tb  = (int*)(ws + WS_TB);
    int s = 0, ts = 0;
    for (int p = 0; p < NPAIR; ++p) {
      bas[p] = s; cur[p] = s; tb[p] = ts;
      s  += cnt[p];
      ts += (cnt[p] + 63) >> 6;
    }
    bas[NPAIR] = s; tb[NPAIR] = ts;
    const float* Se = (const float*)(ws + WS_SE);
    float a = 0.f;
    for (int e = 0; e < NE; ++e) { float m = Se[e] * (1.f / (float)N_TOK); a += m * m; }
    *aux_out = (float)NE * a;
  }
}

// =====================================================================
// K1c: compact tokens into pair buckets
// =====================================================================
__global__ __launch_bounds__(256) void k_place(char* __restrict__ ws)
{
  __shared__ int lcnt[NPAIR], lbase[NPAIR];
  const int tid = threadIdx.x;
  if (tid < NPAIR) lcnt[tid] = 0;
  __syncthreads();
  const int n = blockIdx.x * 256 + tid;
  unsigned int pr = ((const unsigned int*)(ws + WS_PAIR))[n];
  const int p = (int)(pr & 255u) * NE + (int)((pr >> 8) & 255u);
  int loc = atomicAdd(&lcnt[p], 1);
  __syncthreads();
  if (tid < NPAIR && lcnt[tid]) lbase[tid] = atomicAdd((int*)(ws + WS_CUR) + tid, lcnt[tid]);
  __syncthreads();
  ((int*)(ws + WS_LIST))[lbase[p] + loc] = n;
}

// =====================================================================
// K2: fused expert compute, one (pair,tile) of 64 tokens per block.
// Sequential-buffer plan (45KB LDS -> 3 blocks/CU):
//   stage XS | S1: XS->BUF | S2: BUF->HS2 | T1a: XS->BUF (+S3) |
//   T2a: BUF->acc2(K 0..127) | T1b: XS->BUF | T2b: BUF->acc2(K 128..255) |
//   W2: acc2 -> H2 (cols 0..127 into XS region, 128..255 into BUF) |
//   T3: XS+BUF -> acc3, fold w*(acc3+b) into tacc.
// =====================================================================
__global__ __launch_bounds__(256, 3) void k_expert(
    const float* __restrict__ xg,
    const float* __restrict__ tb1, const float* __restrict__ tb2, const float* __restrict__ tb3,
    const float* __restrict__ sb1, const float* __restrict__ sb2, const float* __restrict__ sb3,
    const float* __restrict__ sw3,
    float* __restrict__ traj_out, float* __restrict__ sc_out,
    const char* __restrict__ ws)
{
  __shared__ __attribute__((aligned(16))) char sm[SM_BYTES];
  const int tid  = threadIdx.x;
  const int lane = tid & 63, w = tid >> 6;
  const int l15  = lane & 15, quad = lane >> 4;

  const int* tb = (const int*)(ws + WS_TB);
  const int b = blockIdx.x;
  if (b >= tb[NPAIR]) return;
  int p = 0;
  #pragma unroll 1
  for (int q = 1; q < NPAIR; ++q) if (b >= tb[q]) p = q;
  const int t = b - tb[p];
  const int* bas = (const int*)(ws + WS_BAS);
  const int segbase = bas[p];
  const int cnt = bas[p + 1] - segbase;
  const int e1 = p / NE, e2 = p - e1 * NE;

  int* tokv = (int*)(sm + TOK_OFF);
  if (tid < 64) {
    const int o = t * 64 + tid;
    const bool valid = o < cnt;
    int tok = valid ? ((const int*)(ws + WS_LIST))[segbase + o] : -1;
    tokv[tid] = tok;
    ((float*)(sm + WA_OFF))[tid] = valid ? ((const float*)(ws + WS_W1A))[tok] : 0.f;
    ((float*)(sm + WB_OFF))[tid] = valid ? ((const float*)(ws + WS_W2A))[tok] : 0.f;
  }
  __syncthreads();

  const short* fragw = (const short*)(ws + WS_FRAG);
  const f32x4 z = {0.f, 0.f, 0.f, 0.f};
  f32x4 tacc[4][2];
  #pragma unroll
  for (int mt = 0; mt < 4; ++mt) { tacc[mt][0] = z; tacc[mt][1] = z; }

  #pragma unroll 1
  for (int s = 0; s < 2; ++s) {
    const int e = s ? e2 : e1;
    const short* fb = fragw + (size_t)e * EOFF;
    const int woff = s ? WB_OFF : WA_OFF;

    { // stage XS (x -> bf16, stride 136)
      const int r = tid >> 2, seg = tid & 3;
      int tok = tokv[r]; if (tok < 0) tok = 0;
      const float4* src = (const float4*)(xg + (size_t)tok * 128 + seg * 32);
      unsigned int* dst = (unsigned int*)((short*)(sm + XS_OFF) + r * 136 + seg * 32);
      #pragma unroll
      for (int i = 0; i < 8; ++i) {
        float4 v = src[i];
        dst[i*2+0] = (unsigned int)(unsigned short)f2bf(v.x) | ((unsigned int)(unsigned short)f2bf(v.y) << 16);
        dst[i*2+1] = (unsigned int)(unsigned short)f2bf(v.z) | ((unsigned int)(unsigned short)f2bf(v.w) << 16);
      }
    }
    __syncthreads();

    { // S1: XS * sW1 -> BUF (HS1, 64x128)
      f32x4 acc[4][2];
      #pragma unroll
      for (int mt = 0; mt < 4; ++mt) { acc[mt][0] = z; acc[mt][1] = z; }
      gemm_g<4, 4, 2, 4>(sm, XS_OFF, 136, fb + FOFF_SW1, w * 2, acc, lane);
      epi_gelu<4, 2>(sm, BUF_OFF, 136, sb1 + e * 128, acc, w * 2, lane);
    }
    __syncthreads();

    { // S2: BUF(HS1) * sW2 -> HS2 (64x64)
      f32x4 acc[4][1];
      #pragma unroll
      for (int mt = 0; mt < 4; ++mt) acc[mt][0] = z;
      gemm_g<4, 4, 1, 4>(sm, BUF_OFF, 136, fb + FOFF_SW2, w, acc, lane);
      epi_gelu<4, 1>(sm, HS2_OFF, 72, sb2 + e * 64, acc, w, lane);
    }
    __syncthreads();

    { // T1a: XS * tW1[:,0:128] -> BUF ; S3 fused (4 threads/token on HS2)
      f32x4 acc[4][2];
      #pragma unroll
      for (int mt = 0; mt < 4; ++mt) { acc[mt][0] = z; acc[mt][1] = z; }
      gemm_g<4, 4, 2, 4>(sm, XS_OFF, 136, fb + FOFF_TW1, w * 2, acc, lane);
      // S3: token r = tid>>2, quarter kq = tid&3 (16 MACs each), quad shfl-reduce
      {
        const int r = tid >> 2, kq = tid & 3;
        const short* h = (const short*)(sm + HS2_OFF) + r * 72 + kq * 16;
        const float* w3e = sw3 + e * 64 + kq * 16;
        float sacc = 0.f;
        #pragma unroll
        for (int kk = 0; kk < 2; ++kk) {
          short8 v8 = *(const short8*)(h + kk * 8);
          #pragma unroll
          for (int j = 0; j < 8; ++j) sacc = fmaf(bf2f(v8[j]), w3e[kk * 8 + j], sacc);
        }
        sacc += __shfl_xor(sacc, 1);
        sacc += __shfl_xor(sacc, 2);
        if (kq == 0) {
          float c = ((float*)(sm + woff))[r] * (sacc + sb3[e]);
          float* scl = (float*)(sm + SC_OFF);
          if (s == 0) scl[r] = c; else scl[r] += c;
        }
      }
      epi_gelu<4, 2>(sm, BUF_OFF, 136, tb1 + e * 256, acc, w * 2, lane);
    }
    __syncthreads();

    // T2: H1 * tW2 with K-split; acc2 persists across phases
    f32x4 acc2[4][4];
    #pragma unroll
    for (int mt = 0; mt < 4; ++mt)
      #pragma unroll
      for (int ntl = 0; ntl < 4; ++ntl) acc2[mt][ntl] = z;

    // T2a: K 0..127 (BUF = H1a)
    gemm_g<4, 4, 4, 8>(sm, BUF_OFF, 136, fb + FOFF_TW2, w * 4, acc2, lane);
    __syncthreads();

    { // T1b: XS * tW1[:,128:256] -> BUF (H1b)
      f32x4 acc[4][2];
      #pragma unroll
      for (int mt = 0; mt < 4; ++mt) { acc[mt][0] = z; acc[mt][1] = z; }
      gemm_g<4, 4, 2, 4>(sm, XS_OFF, 136, fb + FOFF_TW1 + 8 * 4 * 512, w * 2, acc, lane);
      epi_gelu<4, 2>(sm, BUF_OFF, 136, tb1 + e * 256 + 128, acc, w * 2, lane);
    }
    __syncthreads();

    // T2b: K 128..255 (BUF = H1b; B kt offset +4)
    gemm_g<4, 4, 4, 8>(sm, BUF_OFF, 136, fb + FOFF_TW2 + 4 * 512, w * 4, acc2, lane);
    __syncthreads();

    { // W2: acc2 -> H2; cols 0..127 into XS region, 128..255 into BUF
      const float* bb = tb2 + e * 256;
      #pragma unroll
      for (int ntl = 0; ntl < 4; ++ntl) {
        const int n = (w * 4 + ntl) * 16 + l15;
        const float bv = bb[n];
        #pragma unroll
        for (int mt = 0; mt < 4; ++mt) {
          #pragma unroll
          for (int i = 0; i < 4; ++i) {
            const int r = mt * 16 + quad * 4 + i;
            short vbf = f2bf(gelu_fast(acc2[mt][ntl][i] + bv));
            if (n < 128) ((short*)(sm + XS_OFF))[r * 136 + n] = vbf;
            else         ((short*)(sm + BUF_OFF))[r * 136 + (n - 128)] = vbf;
          }
        }
      }
    }
    __syncthreads();

    { // T3: H2 * tW3 (K 0..127 from XS region, 128..255 from BUF)
      f32x4 acc3[4][2];
      #pragma unroll
      for (int mt = 0; mt < 4; ++mt) { acc3[mt][0] = z; acc3[mt][1] = z; }
      gemm_g<4, 4, 2, 8>(sm, XS_OFF, 136, fb + FOFF_TW3, w * 2, acc3, lane);
      gemm_g<4, 4, 2, 8>(sm, BUF_OFF, 136, fb + FOFF_TW3 + 4 * 512, w * 2, acc3, lane);
      const float* wl = (const float*)(sm + woff);
      f32x4 wv[4];
      #pragma unroll
      for (int mt = 0; mt < 4; ++mt) wv[mt] = *(const f32x4*)(wl + mt * 16 + quad * 4);
      #pragma unroll
      for (int ntl = 0; ntl < 2; ++ntl) {
        const int nn = (w * 2 + ntl) * 16 + l15;
        float bv = (nn < TCOL) ? tb3[e * TCOL + nn] : 0.f;
        #pragma unroll
        for (int mt = 0; mt < 4; ++mt)
          #pragma unroll
          for (int i = 0; i < 4; ++i)
            tacc[mt][ntl][i] += wv[mt][i] * (acc3[mt][ntl][i] + bv);
      }
    }
    __syncthreads();
  }

  // final stores (exactly-once per token)
  #pragma unroll
  for (int ntl = 0; ntl < 2; ++ntl) {
    const int nn = (w * 2 + ntl) * 16 + l15;
    if (nn < TCOL) {
      #pragma unroll
      for (int mt = 0; mt < 4; ++mt) {
        #pragma unroll
        for (int i = 0; i < 4; ++i) {
          const int r = mt * 16 + quad * 4 + i;
          const int tok = tokv[r];
          if (tok >= 0) traj_out[(size_t)tok * TCOL + nn] = tacc[mt][ntl][i];
        }
      }
    }
  }
  if (tid < 64) {
    const int tok = tokv[tid];
    if (tok >= 0) sc_out[tok] = ((float*)(sm + SC_OFF))[tid];
  }
}

// =====================================================================
extern "C" void kernel_launch(void* const* d_in, const int* in_sizes, int n_in,
                              void* d_out, int out_size, void* d_ws, size_t ws_size,
                              hipStream_t stream)
{
  const float* x   = (const float*)d_in[0];
  const float* rW1 = (const float*)d_in[1];  const float* rb1 = (const float*)d_in[2];
  const float* rW2 = (const float*)d_in[3];  const float* rb2 = (const float*)d_in[4];
  const float* rW3 = (const float*)d_in[5];  const float* rb3 = (const float*)d_in[6];
  const float* tW1 = (const float*)d_in[7];  const float* tb1 = (const float*)d_in[8];
  const float* tW2 = (const float*)d_in[9];  const float* tb2 = (const float*)d_in[10];
  const float* tW3 = (const float*)d_in[11]; const float* tb3 = (const float*)d_in[12];
  const float* sW1 = (const float*)d_in[13]; const float* sb1 = (const float*)d_in[14];
  const float* sW2 = (const float*)d_in[15]; const float* sb2 = (const float*)d_in[16];
  const float* sW3 = (const float*)d_in[17]; const float* sb3 = (const float*)d_in[18];
  char* ws = (char*)d_ws;
  float* out    = (float*)d_out;
  float* traj   = out;                       // [N,120]
  float* scores = out + 11796480;            // [N]
  float* aux    = out + 11894784;            // scalar
  float* probs  = out + 11894785;            // [N,6]

  hipMemsetAsync(d_ws, 0, 512, stream);      // zero SE + CNT + RCNT

  hipLaunchKernelGGL(k_prep, dim3(620), dim3(256), 0, stream,
                     rW1, rW2, rW3, tW1, tW2, tW3, sW1, sW2, ws);

  hipLaunchKernelGGL(k_router2, dim3(N_TOK / 32), dim3(256), 0, stream,
                     x, rb1, rb2, rb3, probs, ws);

  hipLaunchKernelGGL(k_repair, dim3(256), dim3(256), 0, stream,
                     x, rb1, rW2, rb2, rb3, probs, ws);

  hipLaunchKernelGGL(k_count, dim3(N_TOK / 256), dim3(256), 0, stream, ws);

  hipLaunchKernelGGL(k_scan, dim3(1), dim3(64), 0, stream, ws, aux);

  hipLaunchKernelGGL(k_place, dim3(N_TOK / 256), dim3(256), 0, stream, ws);

  hipLaunchKernelGGL(k_expert, dim3(1600), dim3(256), 0, stream,
                     x, tb1, tb2, tb3, sb1, sb2, sb3, sW3, traj, scores, ws);
}

// Round 4
// 429.894 us; speedup vs baseline: 2.7707x; 2.7707x over previous
//
#include <hip/hip_runtime.h>
#include <math.h>

// ---------------- problem constants ----------------
#define N_TOK  98304   // B*M
#define NE     6
#define NPAIR  36      // ordered (e1,e2) pairs, e1*6+e2
#define TCOL   120     // T*2
#define RMARGIN 1.0e-3f  // gap(v2,v3) threshold for fp32 repair (split router err ~1.5e-5)

// ---------------- workspace byte offsets ----------------
#define WS_SE    0         // float[8]  : per-expert prob sums (atomic)
#define WS_CNT   32        // int[36]   : pair counts (atomic)
#define WS_CUR   192       // int[36]   : placement cursors
#define WS_BAS   352       // int[37]   : pair bases (prefix), bas[36]=N
#define WS_RCNT  504       // int       : repair count (zeroed by memset 512)
#define WS_TB    512       // int[37]   : pair tile bases
#define WS_PAIR  1024      // uint[N]   : e1 | e2<<8
#define WS_W1A   394240    // float[N]  : top-1 weight
#define WS_W2A   787456    // float[N]  : top-2 weight
#define WS_LIST  1180672   // int[N]    : repair list, then pair-bucketed tokens
#define WS_RW1T  1573888   // float[256*128] : router W1 transposed [c][k] (repair)
#define WS_RW3T  1704960   // float[6*128]   : router W3 transposed [e][j] (repair)
#define WS_FRAG  1708032   // bf16 expert weights, MFMA-B-fragment layout
#define WS_RFRAG 3575808   // bf16 router weight frags hi/lo (135168 el = 270336 B)
#define WS_RW2T  3846144   // float[128*256] : router W2 transposed [c][k] (repair)

// expert fragment offsets (bf16 elements)
#define EOFF      155648
#define FOFF_TW1  0
#define FOFF_TW2  32768
#define FOFF_TW3  98304
#define FOFF_SW1  131072
#define FOFF_SW2  147456

// router fragment offsets (bf16 elements within WS_RFRAG)
#define RF_W1HI 0
#define RF_W1LO 32768
#define RF_W2HI 65536
#define RF_W2LO 98304
#define RF_W3HI 131072
#define RF_W3LO 133120

// ---------------- K2 (expert) LDS layout (R2-validated, 78848 B) ----------
#define XS_OFF   0
#define HS1_OFF  17408
#define H2_OFF   0
#define H1_OFF   34816
#define HS2_OFF  68608
#define TOK_OFF  77824
#define WA_OFF   78080
#define WB_OFF   78336
#define SC_OFF   78592
#define SM_BYTES 78848

// ---------------- routerS LDS layout (32-token blocks, split) -------------
#define RXHI  0        // 32x136 bf16 = 8704
#define RXLO  8704
#define RH2HI 0        // overlay (X dead after L1)
#define RH2LO 8704
#define RH1HI 17408    // 32x264 bf16 = 16896
#define RH1LO 34304
#define RLG   51200    // 32x8 fp32 = 1024
#define SRED  52224    // float[6]
#define RSM_BYTES 52256   // 3 blocks/CU

typedef short short8 __attribute__((ext_vector_type(8)));
typedef float f32x4  __attribute__((ext_vector_type(4)));

__device__ __forceinline__ short f2bf(float f) {          // RNE fp32 -> bf16
  unsigned int u = __builtin_bit_cast(unsigned int, f);
  u = u + 0x7FFFu + ((u >> 16) & 1u);
  return (short)(u >> 16);
}
__device__ __forceinline__ float bf2f(short s) {
  unsigned int u = ((unsigned int)(unsigned short)s) << 16;
  return __builtin_bit_cast(float, u);
}
// near-exact GELU via A&S 7.1.26 poly erf (|erf err| <= 1.5e-7, HW exp2)
__device__ __forceinline__ float gelu_ref(float x) {
  float z = fabsf(x) * 0.7071067811865476f;
  float t = __builtin_amdgcn_rcpf(fmaf(0.3275911f, z, 1.0f));
  float poly = t * fmaf(t, fmaf(t, fmaf(t, fmaf(t, 1.061405429f, -1.453152027f),
                         1.421413741f), -0.284496736f), 0.254829592f);
  float e = 1.0f - poly * exp2f(-z * z * 1.4426950408889634f);
  float erfv = (x < 0.f) ? -e : e;
  return 0.5f * x * (1.0f + erfv);
}
// fast tanh-GELU (expert path only; tol 0.034)
__device__ __forceinline__ float gelu_fast(float x) {
  float x2 = x * x;
  float u  = x * fmaf(0.1029454f, x2, 2.3021188f);
  float d  = 1.0f + exp2f(-u);
  return x * __builtin_amdgcn_rcpf(d);
}

// =====================================================================
// K0: weight preprocessing.
//  [0,456): expert weights -> bf16 B-frag layout
//  [456,489): router weights -> bf16 hi/lo B-frag pairs
//  [489,620): fp32 transposes W1T + W3T (repair)
//  [620,748): fp32 transpose W2T (repair)
// B-frag: tile(nt,kt): lane l holds B[k=kt*32+(l>>4)*8+j][n=nt*16+(l&15)]
// =====================================================================
__global__ __launch_bounds__(256) void k_prep(
    const float* __restrict__ rW1, const float* __restrict__ rW2,
    const float* __restrict__ rW3,
    const float* __restrict__ tW1, const float* __restrict__ tW2,
    const float* __restrict__ tW3, const float* __restrict__ sW1,
    const float* __restrict__ sW2, char* __restrict__ ws)
{
  const int tid = threadIdx.x, blk = blockIdx.x;
  const int lane = tid & 63, l15 = lane & 15, quad = lane >> 4;
  if (blk < 456) {                       // 1824 expert tiles, 1 wave each
    const int g = blk * 4 + (tid >> 6);
    const int e = g / 304, r = g - e * 304;
    const float* src; int KT, Nreal, dstoff, nt, kt;
    if (r < 64)       { KT=4; src=tW1+e*32768; Nreal=256; dstoff=FOFF_TW1; kt=r&3;        nt=r>>2; }
    else if (r < 192) { int r2=r-64;  KT=8; src=tW2+e*65536; Nreal=256; dstoff=FOFF_TW2; kt=r2&7; nt=r2>>3; }
    else if (r < 256) { int r2=r-192; KT=8; src=tW3+e*30720; Nreal=120; dstoff=FOFF_TW3; kt=r2&7; nt=r2>>3; }
    else if (r < 288) { int r2=r-256; KT=4; src=sW1+e*16384; Nreal=128; dstoff=FOFF_SW1; kt=r2&3; nt=r2>>2; }
    else              { int r2=r-288; KT=4; src=sW2+e*8192;  Nreal=64;  dstoff=FOFF_SW2; kt=r2&3; nt=r2>>2; }
    const int n = nt * 16 + l15;
    short8 v;
    #pragma unroll
    for (int j = 0; j < 8; ++j) {
      int k = kt * 32 + quad * 8 + j;
      float f = (n < Nreal) ? src[k * Nreal + n] : 0.f;
      v[j] = f2bf(f);
    }
    short* dst = (short*)(ws + WS_FRAG) + (size_t)e * EOFF + dstoff + (nt * KT + kt) * 512 + lane * 8;
    *(short8*)dst = v;
  } else if (blk < 489) {                // 132 router tiles (hi+lo), 1 wave each
    const int g = (blk - 456) * 4 + (tid >> 6);   // 0..131
    const float* src; int KT, Nreal, kt, nt, dhi, dlo;
    if (g < 64)       { KT=4; src=rW1; Nreal=256; kt=g&3; nt=g>>2; dhi=RF_W1HI; dlo=RF_W1LO; }
    else if (g < 128) { int g2=g-64; KT=8; src=rW2; Nreal=128; kt=g2&7; nt=g2>>3; dhi=RF_W2HI; dlo=RF_W2LO; }
    else              { int g2=g-128; KT=4; src=rW3; Nreal=6;  kt=g2;   nt=0;     dhi=RF_W3HI; dlo=RF_W3LO; }
    const int n = nt * 16 + l15;
    short8 vh, vl;
    #pragma unroll
    for (int j = 0; j < 8; ++j) {
      int k = kt * 32 + quad * 8 + j;
      float f = (n < Nreal) ? src[k * Nreal + n] : 0.f;
      short hi = f2bf(f);
      vh[j] = hi;
      vl[j] = f2bf(f - bf2f(hi));
    }
    short* base = (short*)(ws + WS_RFRAG);
    const int idx = (nt * KT + kt) * 512 + lane * 8;
    *(short8*)(base + dhi + idx) = vh;
    *(short8*)(base + dlo + idx) = vl;
  } else if (blk < 620) {                // W1T + W3T
    const int t = (blk - 489) * 256 + tid;
    if (t < 32768) {
      int c = t >> 7, k = t & 127;
      ((float*)(ws + WS_RW1T))[t] = rW1[k * 256 + c];
    } else if (t < 33536) {
      int t2 = t - 32768, e = t2 >> 7, j = t2 & 127;
      ((float*)(ws + WS_RW3T))[t2] = rW3[j * 6 + e];
    }
  } else {                               // W2T: [c][k], c=0..127, k=0..255
    const int t = (blk - 620) * 256 + tid;   // 0..32767
    int c = t >> 8, k = t & 255;
    ((float*)(ws + WS_RW2T))[t] = rW2[k * 128 + c];
  }
}

// =====================================================================
// K1: split-bf16 MFMA router (hi*hi + hi*lo + lo*hi), all tokens.
// 32 tokens/block, 4 waves, 3 blocks/CU. Margin 1e-3 -> fp32 repair list.
// =====================================================================
__global__ __launch_bounds__(256) void k_routerS(
    const float* __restrict__ xg,
    const float* __restrict__ b1, const float* __restrict__ b2,
    const float* __restrict__ b3,
    float* __restrict__ probs_out, char* __restrict__ ws)
{
  __shared__ __attribute__((aligned(16))) char sm[RSM_BYTES];
  const int tid = threadIdx.x;
  const int lane = tid & 63, w = tid >> 6;
  const int l15 = lane & 15, quad = lane >> 4;
  const int tok0 = blockIdx.x * 32;
  const short* rf = (const short*)(ws + WS_RFRAG);
  const f32x4 z = {0.f, 0.f, 0.f, 0.f};

  if (tid < NE) ((float*)(sm + SRED))[tid] = 0.f;

  // stage X hi/lo (consecutive tokens -> coalesced)
  {
    const int t = tid >> 3, seg = tid & 7;
    const float4* src = (const float4*)(xg + (size_t)(tok0 + t) * 128 + seg * 16);
    unsigned int* dhi = (unsigned int*)((short*)(sm + RXHI) + t * 136 + seg * 16);
    unsigned int* dlo = (unsigned int*)((short*)(sm + RXLO) + t * 136 + seg * 16);
    #pragma unroll
    for (int i = 0; i < 4; ++i) {
      float4 v = src[i];
      float f0=v.x, f1=v.y, f2=v.z, f3=v.w;
      short h0=f2bf(f0), h1=f2bf(f1), h2=f2bf(f2), h3=f2bf(f3);
      short o0=f2bf(f0-bf2f(h0)), o1=f2bf(f1-bf2f(h1)), o2=f2bf(f2-bf2f(h2)), o3=f2bf(f3-bf2f(h3));
      dhi[i*2+0] = (unsigned int)(unsigned short)h0 | ((unsigned int)(unsigned short)h1 << 16);
      dhi[i*2+1] = (unsigned int)(unsigned short)h2 | ((unsigned int)(unsigned short)h3 << 16);
      dlo[i*2+0] = (unsigned int)(unsigned short)o0 | ((unsigned int)(unsigned short)o1 << 16);
      dlo[i*2+1] = (unsigned int)(unsigned short)o2 | ((unsigned int)(unsigned short)o3 << 16);
    }
  }
  __syncthreads();

  // ---- L1: X[32x128] * W1 -> H1[32x256] ----
  {
    f32x4 acc[2][4];
    #pragma unroll
    for (int mt = 0; mt < 2; ++mt)
      #pragma unroll
      for (int ntl = 0; ntl < 4; ++ntl) acc[mt][ntl] = z;
    #pragma unroll
    for (int kt = 0; kt < 4; ++kt) {
      short8 ahi[2], alo[2];
      #pragma unroll
      for (int mt = 0; mt < 2; ++mt) {
        const int ro = (mt * 16 + l15) * 136 + kt * 32 + quad * 8;
        ahi[mt] = *(const short8*)((short*)(sm + RXHI) + ro);
        alo[mt] = *(const short8*)((short*)(sm + RXLO) + ro);
      }
      #pragma unroll
      for (int ntl = 0; ntl < 4; ++ntl) {
        const int nt = w * 4 + ntl;
        const int fi = (nt * 4 + kt) * 512 + lane * 8;
        short8 bhi = *(const short8*)(rf + RF_W1HI + fi);
        short8 blo = *(const short8*)(rf + RF_W1LO + fi);
        #pragma unroll
        for (int mt = 0; mt < 2; ++mt) {
          acc[mt][ntl] = __builtin_amdgcn_mfma_f32_16x16x32_bf16(ahi[mt], bhi, acc[mt][ntl], 0, 0, 0);
          acc[mt][ntl] = __builtin_amdgcn_mfma_f32_16x16x32_bf16(ahi[mt], blo, acc[mt][ntl], 0, 0, 0);
          acc[mt][ntl] = __builtin_amdgcn_mfma_f32_16x16x32_bf16(alo[mt], bhi, acc[mt][ntl], 0, 0, 0);
        }
      }
    }
    #pragma unroll
    for (int ntl = 0; ntl < 4; ++ntl) {
      const int n = (w * 4 + ntl) * 16 + l15;
      const float bv = b1[n];
      #pragma unroll
      for (int mt = 0; mt < 2; ++mt) {
        #pragma unroll
        for (int i = 0; i < 4; ++i) {
          const int r = mt * 16 + quad * 4 + i;
          float f = gelu_ref(acc[mt][ntl][i] + bv);
          short hi = f2bf(f);
          ((short*)(sm + RH1HI))[r * 264 + n] = hi;
          ((short*)(sm + RH1LO))[r * 264 + n] = f2bf(f - bf2f(hi));
        }
      }
    }
  }
  __syncthreads();

  // ---- L2: H1[32x256] * W2 -> H2[32x128] (overlays X) ----
  {
    f32x4 acc[2][2];
    #pragma unroll
    for (int mt = 0; mt < 2; ++mt) { acc[mt][0] = z; acc[mt][1] = z; }
    #pragma unroll
    for (int kt = 0; kt < 8; ++kt) {
      short8 ahi[2], alo[2];
      #pragma unroll
      for (int mt = 0; mt < 2; ++mt) {
        const int ro = (mt * 16 + l15) * 264 + kt * 32 + quad * 8;
        ahi[mt] = *(const short8*)((short*)(sm + RH1HI) + ro);
        alo[mt] = *(const short8*)((short*)(sm + RH1LO) + ro);
      }
      #pragma unroll
      for (int ntl = 0; ntl < 2; ++ntl) {
        const int nt = w * 2 + ntl;
        const int fi = (nt * 8 + kt) * 512 + lane * 8;
        short8 bhi = *(const short8*)(rf + RF_W2HI + fi);
        short8 blo = *(const short8*)(rf + RF_W2LO + fi);
        #pragma unroll
        for (int mt = 0; mt < 2; ++mt) {
          acc[mt][ntl] = __builtin_amdgcn_mfma_f32_16x16x32_bf16(ahi[mt], bhi, acc[mt][ntl], 0, 0, 0);
          acc[mt][ntl] = __builtin_amdgcn_mfma_f32_16x16x32_bf16(ahi[mt], blo, acc[mt][ntl], 0, 0, 0);
          acc[mt][ntl] = __builtin_amdgcn_mfma_f32_16x16x32_bf16(alo[mt], bhi, acc[mt][ntl], 0, 0, 0);
        }
      }
    }
    #pragma unroll
    for (int ntl = 0; ntl < 2; ++ntl) {
      const int n = (w * 2 + ntl) * 16 + l15;
      const float bv = b2[n];
      #pragma unroll
      for (int mt = 0; mt < 2; ++mt) {
        #pragma unroll
        for (int i = 0; i < 4; ++i) {
          const int r = mt * 16 + quad * 4 + i;
          float f = gelu_ref(acc[mt][ntl][i] + bv);
          short hi = f2bf(f);
          ((short*)(sm + RH2HI))[r * 136 + n] = hi;
          ((short*)(sm + RH2LO))[r * 136 + n] = f2bf(f - bf2f(hi));
        }
      }
    }
  }
  __syncthreads();

  // ---- L3: H2[32x128] * W3 -> logits (waves 0,1 only) ----
  if (w < 2) {
    f32x4 acc = z;
    #pragma unroll
    for (int kt = 0; kt < 4; ++kt) {
      const int ro = (w * 16 + l15) * 136 + kt * 32 + quad * 8;
      short8 ahi = *(const short8*)((short*)(sm + RH2HI) + ro);
      short8 alo = *(const short8*)((short*)(sm + RH2LO) + ro);
      const int fi = kt * 512 + lane * 8;
      short8 bhi = *(const short8*)(rf + RF_W3HI + fi);
      short8 blo = *(const short8*)(rf + RF_W3LO + fi);
      acc = __builtin_amdgcn_mfma_f32_16x16x32_bf16(ahi, bhi, acc, 0, 0, 0);
      acc = __builtin_amdgcn_mfma_f32_16x16x32_bf16(ahi, blo, acc, 0, 0, 0);
      acc = __builtin_amdgcn_mfma_f32_16x16x32_bf16(alo, bhi, acc, 0, 0, 0);
    }
    if (l15 < NE) {
      const float bv = b3[l15];
      #pragma unroll
      for (int i = 0; i < 4; ++i) {
        const int r = w * 16 + quad * 4 + i;
        ((float*)(sm + RLG))[r * 8 + l15] = acc[i] + bv;
      }
    }
  }
  __syncthreads();

  // ---- per-token: top-2, probs, repair flag ----
  if (tid < 32) {
    const int n = tok0 + tid;
    float l[NE];
    #pragma unroll
    for (int e = 0; e < NE; ++e) l[e] = ((float*)(sm + RLG))[tid * 8 + e];
    int e1 = 0; float v1 = l[0];
    #pragma unroll
    for (int e = 1; e < NE; ++e) if (l[e] > v1) { v1 = l[e]; e1 = e; }
    int e2 = -1; float v2 = -3.4e38f;
    #pragma unroll
    for (int e = 0; e < NE; ++e) if (e != e1 && l[e] > v2) { v2 = l[e]; e2 = e; }
    float v3 = -3.4e38f;
    #pragma unroll
    for (int e = 0; e < NE; ++e) if (e != e1 && e != e2 && l[e] > v3) v3 = l[e];

    float ew = expf(v2 - v1);
    float winv = 1.f / (1.f + ew);
    ((unsigned int*)(ws + WS_PAIR))[n] = (unsigned int)e1 | ((unsigned int)e2 << 8);
    ((float*)(ws + WS_W1A))[n] = winv;
    ((float*)(ws + WS_W2A))[n] = ew * winv;

    float s = 0.f;
    #pragma unroll
    for (int e = 0; e < NE; ++e) { l[e] = expf(l[e] - v1); s += l[e]; }
    float inv = 1.f / s;
    float* po = probs_out + (size_t)n * NE;
    #pragma unroll
    for (int e = 0; e < NE; ++e) {
      l[e] *= inv; po[e] = l[e];
      atomicAdd((float*)(sm + SRED) + e, l[e]);
    }
    if (v2 - v3 < RMARGIN) {
      int idx = atomicAdd((int*)(ws + WS_RCNT), 1);
      ((int*)(ws + WS_LIST))[idx] = n;
    }
  }
  __syncthreads();
  if (tid < NE) atomicAdd((float*)(ws + WS_SE) + tid, ((float*)(sm + SRED))[tid]);
}

// =====================================================================
// K1r: fp32 repair, wave per token. All weights contiguous (W1T/W2T/W3T),
// 4-way partial-sum ILP. Expected ~300-500 tokens -> 1 round.
// =====================================================================
__global__ __launch_bounds__(256) void k_repair(
    const float* __restrict__ xg,
    const float* __restrict__ b1, const float* __restrict__ b2,
    const float* __restrict__ b3,
    float* __restrict__ probs_out, char* __restrict__ ws)
{
  __shared__ float xs[4][128], h1b[4][256], h2b[4][128], lgb[4][8];
  const int tid = threadIdx.x, lane = tid & 63, w = tid >> 6;
  const int gw = blockIdx.x * 4 + w, NW = gridDim.x * 4;
  const int rc = *(const int*)(ws + WS_RCNT);
  const float* w1t = (const float*)(ws + WS_RW1T);
  const float* w2t = (const float*)(ws + WS_RW2T);
  const float* w3t = (const float*)(ws + WS_RW3T);

  for (int i = gw; i < rc; i += NW) {
    const int n = ((const int*)(ws + WS_LIST))[i];
    xs[w][lane]      = xg[(size_t)n * 128 + lane];
    xs[w][64 + lane] = xg[(size_t)n * 128 + 64 + lane];
    __builtin_amdgcn_s_waitcnt(0);
    #pragma unroll
    for (int c4 = 0; c4 < 4; ++c4) {
      const int c = c4 * 64 + lane;
      const float* wr = w1t + c * 128;
      float a0 = 0.f, a1 = 0.f, a2 = 0.f, a3 = 0.f;
      #pragma unroll 8
      for (int k = 0; k < 128; k += 4) {
        a0 = fmaf(xs[w][k+0], wr[k+0], a0);
        a1 = fmaf(xs[w][k+1], wr[k+1], a1);
        a2 = fmaf(xs[w][k+2], wr[k+2], a2);
        a3 = fmaf(xs[w][k+3], wr[k+3], a3);
      }
      h1b[w][c] = gelu_ref(b1[c] + (a0 + a1) + (a2 + a3));
    }
    __builtin_amdgcn_s_waitcnt(0);
    #pragma unroll
    for (int c2 = 0; c2 < 2; ++c2) {
      const int c = c2 * 64 + lane;
      const float* wr = w2t + c * 256;
      float a0 = 0.f, a1 = 0.f, a2 = 0.f, a3 = 0.f;
      #pragma unroll 8
      for (int k = 0; k < 256; k += 4) {
        a0 = fmaf(h1b[w][k+0], wr[k+0], a0);
        a1 = fmaf(h1b[w][k+1], wr[k+1], a1);
        a2 = fmaf(h1b[w][k+2], wr[k+2], a2);
        a3 = fmaf(h1b[w][k+3], wr[k+3], a3);
      }
      h2b[w][c] = gelu_ref(b2[c] + (a0 + a1) + (a2 + a3));
    }
    __builtin_amdgcn_s_waitcnt(0);
    if (lane < NE) {
      const float* wr = w3t + lane * 128;
      float a0 = 0.f, a1 = 0.f, a2 = 0.f, a3 = 0.f;
      #pragma unroll 8
      for (int k = 0; k < 128; k += 4) {
        a0 = fmaf(h2b[w][k+0], wr[k+0], a0);
        a1 = fmaf(h2b[w][k+1], wr[k+1], a1);
        a2 = fmaf(h2b[w][k+2], wr[k+2], a2);
        a3 = fmaf(h2b[w][k+3], wr[k+3], a3);
      }
      lgb[w][lane] = b3[lane] + (a0 + a1) + (a2 + a3);
    }
    __builtin_amdgcn_s_waitcnt(0);
    if (lane == 0) {
      float l[NE];
      #pragma unroll
      for (int e = 0; e < NE; ++e) l[e] = lgb[w][e];
      int e1 = 0; float v1 = l[0];
      #pragma unroll
      for (int e = 1; e < NE; ++e) if (l[e] > v1) { v1 = l[e]; e1 = e; }
      int e2 = -1; float v2 = -3.4e38f;
      #pragma unroll
      for (int e = 0; e < NE; ++e) if (e != e1 && l[e] > v2) { v2 = l[e]; e2 = e; }
      float ew = expf(v2 - v1);
      float winv = 1.f / (1.f + ew);
      ((unsigned int*)(ws + WS_PAIR))[n] = (unsigned int)e1 | ((unsigned int)e2 << 8);
      ((float*)(ws + WS_W1A))[n] = winv;
      ((float*)(ws + WS_W2A))[n] = ew * winv;
      float s = 0.f;
      #pragma unroll
      for (int e = 0; e < NE; ++e) { l[e] = expf(l[e] - v1); s += l[e]; }
      float inv = 1.f / s;
      float* po = probs_out + (size_t)n * NE;
      #pragma unroll
      for (int e = 0; e < NE; ++e) po[e] = l[e] * inv;
    }
  }
}

// =====================================================================
// K1c0: pair counts (after repair)
// =====================================================================
__global__ __launch_bounds__(256) void k_count(char* __restrict__ ws)
{
  __shared__ int lcnt[NPAIR];
  const int tid = threadIdx.x;
  if (tid < NPAIR) lcnt[tid] = 0;
  __syncthreads();
  const int n = blockIdx.x * 256 + tid;
  unsigned int pr = ((const unsigned int*)(ws + WS_PAIR))[n];
  atomicAdd(&lcnt[(int)(pr & 255u) * NE + (int)((pr >> 8) & 255u)], 1);
  __syncthreads();
  if (tid < NPAIR && lcnt[tid]) atomicAdd((int*)(ws + WS_CNT) + tid, lcnt[tid]);
}

// =====================================================================
// K1b: serial 36-bucket prefix scan + aux_loss (tiny)
// =====================================================================
__global__ void k_scan(char* __restrict__ ws, float* __restrict__ aux_out)
{
  if (threadIdx.x == 0 && blockIdx.x == 0) {
    int* cnt = (int*)(ws + WS_CNT);
    int* cur = (int*)(ws + WS_CUR);
    int* bas = (int*)(ws + WS_BAS);
    int* tb  = (int*)(ws + WS_TB);
    int s = 0, ts = 0;
    for (int p = 0; p < NPAIR; ++p) {
      bas[p] = s; cur[p] = s; tb[p] = ts;
      s  += cnt[p];
      ts += (cnt[p] + 63) >> 6;
    }
    bas[NPAIR] = s; tb[NPAIR] = ts;
    const float* Se = (const float*)(ws + WS_SE);
    float a = 0.f;
    for (int e = 0; e < NE; ++e) { float m = Se[e] * (1.f / (float)N_TOK); a += m * m; }
    *aux_out = (float)NE * a;
  }
}

// =====================================================================
// K1c: compact tokens into pair buckets
// =====================================================================
__global__ __launch_bounds__(256) void k_place(char* __restrict__ ws)
{
  __shared__ int lcnt[NPAIR], lbase[NPAIR];
  const int tid = threadIdx.x;
  if (tid < NPAIR) lcnt[tid] = 0;
  __syncthreads();
  const int n = blockIdx.x * 256 + tid;
  unsigned int pr = ((const unsigned int*)(ws + WS_PAIR))[n];
  const int p = (int)(pr & 255u) * NE + (int)((pr >> 8) & 255u);
  int loc = atomicAdd(&lcnt[p], 1);
  __syncthreads();
  if (tid < NPAIR && lcnt[tid]) lbase[tid] = atomicAdd((int*)(ws + WS_CUR) + tid, lcnt[tid]);
  __syncthreads();
  ((int*)(ws + WS_LIST))[lbase[p] + loc] = n;
}

// =====================================================================
// K2 helpers (R2-validated)
// =====================================================================
template<int KTILES, int NTW>
__device__ __forceinline__ void gemm_phase(
    const char* sm, int aOff, int aStride,
    const short* __restrict__ bfrag, int ntBase,
    f32x4 (&acc)[4][NTW], int lane)
{
  const int l15 = lane & 15, quad = lane >> 4;
  #pragma unroll
  for (int kt = 0; kt < KTILES; ++kt) {
    short8 a[4];
    #pragma unroll
    for (int mt = 0; mt < 4; ++mt) {
      const short* ap = (const short*)(sm + aOff) + (mt * 16 + l15) * aStride + kt * 32 + quad * 8;
      a[mt] = *(const short8*)ap;
    }
    #pragma unroll
    for (int ntl = 0; ntl < NTW; ++ntl) {
      const int nt = ntBase + ntl;
      short8 b = *(const short8*)(bfrag + (size_t)(nt * KTILES + kt) * 512 + lane * 8);
      #pragma unroll
      for (int mt = 0; mt < 4; ++mt)
        acc[mt][ntl] = __builtin_amdgcn_mfma_f32_16x16x32_bf16(a[mt], b, acc[mt][ntl], 0, 0, 0);
    }
  }
}

template<int NTW>
__device__ __forceinline__ void epi_gelu(
    char* sm, int outOff, int outStride, const float* __restrict__ bias,
    f32x4 (&acc)[4][NTW], int ntBase, int lane)
{
  const int l15 = lane & 15, quad = lane >> 4;
  #pragma unroll
  for (int ntl = 0; ntl < NTW; ++ntl) {
    const int n = (ntBase + ntl) * 16 + l15;
    float bv = bias[n];
    #pragma unroll
    for (int mt = 0; mt < 4; ++mt) {
      #pragma unroll
      for (int i = 0; i < 4; ++i) {
        const int r = mt * 16 + quad * 4 + i;
        ((short*)(sm + outOff))[r * outStride + n] = f2bf(gelu_fast(acc[mt][ntl][i] + bv));
      }
    }
  }
}

// =====================================================================
// K2: fused expert compute, one (pair,tile) of 64 tokens per block.
// R2-validated version (174us measured).
// =====================================================================
__global__ __launch_bounds__(256, 2) void k_expert(
    const float* __restrict__ xg,
    const float* __restrict__ tb1, const float* __restrict__ tb2, const float* __restrict__ tb3,
    const float* __restrict__ sb1, const float* __restrict__ sb2, const float* __restrict__ sb3,
    const float* __restrict__ sw3,
    float* __restrict__ traj_out, float* __restrict__ sc_out,
    const char* __restrict__ ws)
{
  __shared__ __attribute__((aligned(16))) char sm[SM_BYTES];
  const int tid  = threadIdx.x;
  const int lane = tid & 63, w = tid >> 6;
  const int l15  = lane & 15, quad = lane >> 4;

  const int* tb = (const int*)(ws + WS_TB);
  const int b = blockIdx.x;
  if (b >= tb[NPAIR]) return;
  int p = 0;
  #pragma unroll 1
  for (int q = 1; q < NPAIR; ++q) if (b >= tb[q]) p = q;
  const int t = b - tb[p];
  const int* bas = (const int*)(ws + WS_BAS);
  const int segbase = bas[p];
  const int cnt = bas[p + 1] - segbase;
  const int e1 = p / NE, e2 = p - e1 * NE;

  int* tokv = (int*)(sm + TOK_OFF);
  if (tid < 64) {
    const int o = t * 64 + tid;
    const bool valid = o < cnt;
    int tok = valid ? ((const int*)(ws + WS_LIST))[segbase + o] : -1;
    tokv[tid] = tok;
    ((float*)(sm + WA_OFF))[tid] = valid ? ((const float*)(ws + WS_W1A))[tok] : 0.f;
    ((float*)(sm + WB_OFF))[tid] = valid ? ((const float*)(ws + WS_W2A))[tok] : 0.f;
  }
  __syncthreads();

  const short* fragw = (const short*)(ws + WS_FRAG);
  const f32x4 z = {0.f, 0.f, 0.f, 0.f};
  f32x4 tacc[4][2];
  #pragma unroll
  for (int mt = 0; mt < 4; ++mt) { tacc[mt][0] = z; tacc[mt][1] = z; }

  #pragma unroll 1
  for (int s = 0; s < 2; ++s) {
    const int e = s ? e2 : e1;
    const short* fb = fragw + (size_t)e * EOFF;
    const int woff = s ? WB_OFF : WA_OFF;

    { // stage XS
      const int r = tid >> 2, seg = tid & 3;
      int tok = tokv[r]; if (tok < 0) tok = 0;
      const float4* src = (const float4*)(xg + (size_t)tok * 128 + seg * 32);
      short* dst = (short*)(sm + XS_OFF) + r * 136 + seg * 32;
      #pragma unroll
      for (int i = 0; i < 8; ++i) {
        float4 v = src[i];
        unsigned int a = (unsigned int)(unsigned short)f2bf(v.x) | ((unsigned int)(unsigned short)f2bf(v.y) << 16);
        unsigned int c = (unsigned int)(unsigned short)f2bf(v.z) | ((unsigned int)(unsigned short)f2bf(v.w) << 16);
        ((unsigned int*)dst)[i * 2 + 0] = a;
        ((unsigned int*)dst)[i * 2 + 1] = c;
      }
    }
    __syncthreads();

    { // S1
      f32x4 acc[4][2];
      #pragma unroll
      for (int mt = 0; mt < 4; ++mt) { acc[mt][0] = z; acc[mt][1] = z; }
      gemm_phase<4, 2>(sm, XS_OFF, 136, fb + FOFF_SW1, w * 2, acc, lane);
      epi_gelu<2>(sm, HS1_OFF, 136, sb1 + e * 128, acc, w * 2, lane);
    }
    __syncthreads();

    { // S2
      f32x4 acc[4][1];
      #pragma unroll
      for (int mt = 0; mt < 4; ++mt) acc[mt][0] = z;
      gemm_phase<4, 1>(sm, HS1_OFF, 136, fb + FOFF_SW2, w, acc, lane);
      epi_gelu<1>(sm, HS2_OFF, 72, sb2 + e * 64, acc, w, lane);
    }
    __syncthreads();

    if (tid < 64) { // S3
      const short* h = (const short*)(sm + HS2_OFF) + tid * 72;
      const float* w3e = sw3 + e * 64;
      float acc = 0.f;
      #pragma unroll
      for (int kk = 0; kk < 8; ++kk) {
        short8 v8 = *(const short8*)(h + kk * 8);
        #pragma unroll
        for (int j = 0; j < 8; ++j) acc = fmaf(bf2f(v8[j]), w3e[kk * 8 + j], acc);
      }
      acc += sb3[e];
      float c = ((float*)(sm + woff))[tid] * acc;
      float* scl = (float*)(sm + SC_OFF);
      if (s == 0) scl[tid] = c; else scl[tid] += c;
    }

    { // T1
      f32x4 acc[4][4];
      #pragma unroll
      for (int mt = 0; mt < 4; ++mt)
        #pragma unroll
        for (int ntl = 0; ntl < 4; ++ntl) acc[mt][ntl] = z;
      gemm_phase<4, 4>(sm, XS_OFF, 136, fb + FOFF_TW1, w * 4, acc, lane);
      epi_gelu<4>(sm, H1_OFF, 264, tb1 + e * 256, acc, w * 4, lane);
    }
    __syncthreads();

    { // T2
      f32x4 acc[4][4];
      #pragma unroll
      for (int mt = 0; mt < 4; ++mt)
        #pragma unroll
        for (int ntl = 0; ntl < 4; ++ntl) acc[mt][ntl] = z;
      gemm_phase<8, 4>(sm, H1_OFF, 264, fb + FOFF_TW2, w * 4, acc, lane);
      epi_gelu<4>(sm, H2_OFF, 264, tb2 + e * 256, acc, w * 4, lane);
    }
    __syncthreads();

    { // T3
      f32x4 acc[4][2];
      #pragma unroll
      for (int mt = 0; mt < 4; ++mt) { acc[mt][0] = z; acc[mt][1] = z; }
      gemm_phase<8, 2>(sm, H2_OFF, 264, fb + FOFF_TW3, w * 2, acc, lane);
      const float* wl = (const float*)(sm + woff);
      f32x4 wv[4];
      #pragma unroll
      for (int mt = 0; mt < 4; ++mt) wv[mt] = *(const f32x4*)(wl + mt * 16 + quad * 4);
      #pragma unroll
      for (int ntl = 0; ntl < 2; ++ntl) {
        const int nn = (w * 2 + ntl) * 16 + l15;
        float bv = (nn < TCOL) ? tb3[e * TCOL + nn] : 0.f;
        #pragma unroll
        for (int mt = 0; mt < 4; ++mt)
          #pragma unroll
          for (int i = 0; i < 4; ++i)
            tacc[mt][ntl][i] += wv[mt][i] * (acc[mt][ntl][i] + bv);
      }
    }
    __syncthreads();
  }

  #pragma unroll
  for (int ntl = 0; ntl < 2; ++ntl) {
    const int nn = (w * 2 + ntl) * 16 + l15;
    if (nn < TCOL) {
      #pragma unroll
      for (int mt = 0; mt < 4; ++mt) {
        #pragma unroll
        for (int i = 0; i < 4; ++i) {
          const int r = mt * 16 + quad * 4 + i;
          const int tok = tokv[r];
          if (tok >= 0) traj_out[(size_t)tok * TCOL + nn] = tacc[mt][ntl][i];
        }
      }
    }
  }
  if (tid < 64) {
    const int tok = tokv[tid];
    if (tok >= 0) sc_out[tok] = ((float*)(sm + SC_OFF))[tid];
  }
}

// =====================================================================
extern "C" void kernel_launch(void* const* d_in, const int* in_sizes, int n_in,
                              void* d_out, int out_size, void* d_ws, size_t ws_size,
                              hipStream_t stream)
{
  const float* x   = (const float*)d_in[0];
  const float* rW1 = (const float*)d_in[1];  const float* rb1 = (const float*)d_in[2];
  const float* rW2 = (const float*)d_in[3];  const float* rb2 = (const float*)d_in[4];
  const float* rW3 = (const float*)d_in[5];  const float* rb3 = (const float*)d_in[6];
  const float* tW1 = (const float*)d_in[7];  const float* tb1 = (const float*)d_in[8];
  const float* tW2 = (const float*)d_in[9];  const float* tb2 = (const float*)d_in[10];
  const float* tW3 = (const float*)d_in[11]; const float* tb3 = (const float*)d_in[12];
  const float* sW1 = (const float*)d_in[13]; const float* sb1 = (const float*)d_in[14];
  const float* sW2 = (const float*)d_in[15]; const float* sb2 = (const float*)d_in[16];
  const float* sW3 = (const float*)d_in[17]; const float* sb3 = (const float*)d_in[18];
  char* ws = (char*)d_ws;
  float* out    = (float*)d_out;
  float* traj   = out;                       // [N,120]
  float* scores = out + 11796480;            // [N]
  float* aux    = out + 11894784;            // scalar
  float* probs  = out + 11894785;            // [N,6]

  hipMemsetAsync(d_ws, 0, 512, stream);      // zero SE + CNT + RCNT

  hipLaunchKernelGGL(k_prep, dim3(748), dim3(256), 0, stream,
                     rW1, rW2, rW3, tW1, tW2, tW3, sW1, sW2, ws);

  hipLaunchKernelGGL(k_routerS, dim3(N_TOK / 32), dim3(256), 0, stream,
                     x, rb1, rb2, rb3, probs, ws);

  hipLaunchKernelGGL(k_repair, dim3(256), dim3(256), 0, stream,
                     x, rb1, rb2, rb3, probs, ws);

  hipLaunchKernelGGL(k_count, dim3(N_TOK / 256), dim3(256), 0, stream, ws);

  hipLaunchKernelGGL(k_scan, dim3(1), dim3(64), 0, stream, ws, aux);

  hipLaunchKernelGGL(k_place, dim3(N_TOK / 256), dim3(256), 0, stream, ws);

  hipLaunchKernelGGL(k_expert, dim3(1600), dim3(256), 0, stream,
                     x, tb1, tb2, tb3, sb1, sb2, sb3, sW3, traj, scores, ws);
}